// Round 21
// baseline (132.762 us; speedup 1.0000x reference)
//
#include <hip/hip_runtime.h>
#include <hip/hip_bf16.h>
#include <math.h>

#define EMBED 1024
#define HEADS 16
#define HDIM 64
#define T_SEQ 4096

typedef __bf16 bf16;
typedef bf16 bf16x4 __attribute__((ext_vector_type(4)));
typedef bf16 bf16x8 __attribute__((ext_vector_type(8)));
typedef float f32x4 __attribute__((ext_vector_type(4)));
typedef float f32x16 __attribute__((ext_vector_type(16)));

// async global->LDS, 16B per lane; LDS dest = wave-uniform base + lane*16.
#define GL(gp, lp)                                                            \
  __builtin_amdgcn_global_load_lds(                                           \
      (const __attribute__((address_space(1))) void*)(gp),                    \
      (__attribute__((address_space(3))) void*)(lp), 16, 0, 0)

// hardware 2^x
__device__ __forceinline__ float fexp2(float x) {
  float r;
  asm("v_exp_f32 %0, %1" : "=v"(r) : "v"(x));
  return r;
}

// ---------------------------------------------------------------------------
// Weight transposes only (x conversion now fused into the QKV GEMM).
// 4096 blocks: bx = b & 127 (col tile), by = b >> 7 (row tile).
// ---------------------------------------------------------------------------
__global__ __launch_bounds__(256) void prep(
    const float* __restrict__ Wqkv, const float* __restrict__ Wout,
    bf16* __restrict__ WqkvT, bf16* __restrict__ WoutT) {
  __shared__ bf16 t[32][33];
  const int b = (int)blockIdx.x;
  const int bx = b & 127, by = b >> 7;
  const int rows = 1024;
  const float* in;
  bf16* out;
  int c0, cols;
  if (bx < 96) { in = Wqkv; out = WqkvT; c0 = bx * 32; cols = 3072; }
  else         { in = Wout; out = WoutT; c0 = (bx - 96) * 32; cols = 1024; }
  const int r0 = by * 32;
  const int tx = threadIdx.x & 31, ty = threadIdx.x >> 5;
#pragma unroll
  for (int i = 0; i < 4; ++i)
    t[ty + 8 * i][tx] = (bf16)in[(size_t)(r0 + ty + 8 * i) * cols + c0 + tx];
  __syncthreads();
#pragma unroll
  for (int i = 0; i < 4; ++i)
    out[(size_t)(c0 + ty + 8 * i) * rows + r0 + tx] = t[tx][ty + 8 * i];
}

// ---------------------------------------------------------------------------
// bf16 MFMA GEMM: C[M][N] = A[M][K] @ BT[N][K]^T + bias[N]
// 128x128 tile, 4 waves, BK=32, single barrier per K-step, XCD-aware grid.
// A_F32: A is fp32 and is reg-staged (issue float4 loads BEFORE compute,
// convert+ds_write AFTER — T14 issue-early/write-late; HBM latency hides
// under the MFMAs). B always stages via async global_load_lds.
// V_TO_VT: column-blocks >= 2048 written transposed into vTout.
// ---------------------------------------------------------------------------
template <bool OUT_F32, bool V_TO_VT, bool A_F32>
__global__ __launch_bounds__(256) void gemm_bt_bias(
    const void* __restrict__ Ain, const bf16* __restrict__ BT,
    const float* __restrict__ bias, void* __restrict__ Cout,
    bf16* __restrict__ vTout, int M, int N, int K) {
  __shared__ __align__(16) bf16 As[2][128 * 32];
  __shared__ __align__(16) bf16 Bs[2][128 * 32];
  const int tid = threadIdx.x;
  const int lane = tid & 63;
  const int w = tid >> 6;
  const int wr = w >> 1, wc = w & 1;
  const int l16 = lane & 15, lq = lane >> 4;

  const int bid = (int)blockIdx.x;
  const int xcd = bid & 7;
  const int local = bid >> 3;
  const int brow = (xcd * 4 + (local & 3)) * 128;
  const int bcol = (local >> 2) * 128;

  const int strow = w * 32 + (lane >> 2);   // staging row (within 128)
  const int stsl = (lane & 3) * 8;          // staging elem offset
  const bf16*  Abf = (const bf16*)Ain + (size_t)(brow + strow) * K + stsl;
  const float* Af  = (const float*)Ain + (size_t)(brow + strow) * K + stsl;
  const bf16*  Bbase = BT + (size_t)(bcol + strow) * K + stsl;

  // --- staging helpers ---
  // B: 2 async GLs.  A(bf16): 2 async GLs.  A(fp32): 4 float4 reg loads,
  // converted+written later by STORE_A.
  f32x4 ra0, ra1, ra2, ra3;
#define ISSUE_STAGE(buf, k0)                                                  \
  {                                                                           \
    if (A_F32) {                                                              \
      ra0 = *(const f32x4*)&Af[(k0)];                                         \
      ra1 = *(const f32x4*)&Af[(k0) + 4];                                     \
      ra2 = *(const f32x4*)&Af[(k0) + (size_t)16 * K];                        \
      ra3 = *(const f32x4*)&Af[(k0) + (size_t)16 * K + 4];                    \
    } else {                                                                  \
      GL(Abf + (k0), &As[buf][(w * 32) * 32]);                                \
      GL(Abf + (k0) + 16 * K, &As[buf][(w * 32 + 16) * 32]);                  \
    }                                                                         \
    GL(Bbase + (k0), &Bs[buf][(w * 32) * 32]);                                \
    GL(Bbase + (k0) + 16 * K, &Bs[buf][(w * 32 + 16) * 32]);                  \
  }
#define STORE_A(buf)                                                          \
  if (A_F32) {                                                                \
    bf16x8 v0, v1;                                                            \
    v0[0] = (bf16)ra0[0]; v0[1] = (bf16)ra0[1]; v0[2] = (bf16)ra0[2];         \
    v0[3] = (bf16)ra0[3]; v0[4] = (bf16)ra1[0]; v0[5] = (bf16)ra1[1];         \
    v0[6] = (bf16)ra1[2]; v0[7] = (bf16)ra1[3];                               \
    v1[0] = (bf16)ra2[0]; v1[1] = (bf16)ra2[1]; v1[2] = (bf16)ra2[2];         \
    v1[3] = (bf16)ra2[3]; v1[4] = (bf16)ra3[0]; v1[5] = (bf16)ra3[1];         \
    v1[6] = (bf16)ra3[2]; v1[7] = (bf16)ra3[3];                               \
    *(bf16x8*)&As[buf][strow * 32 + stsl] = v0;                               \
    *(bf16x8*)&As[buf][(strow + 16) * 32 + stsl] = v1;                        \
  }

  f32x4 acc[4][4] = {};
  const int NIT = K / 32;

  ISSUE_STAGE(0, 0);
  STORE_A(0);
  asm volatile("s_waitcnt vmcnt(0) lgkmcnt(0)" ::: "memory");
  __builtin_amdgcn_s_barrier();

  for (int it = 0; it < NIT; ++it) {
    const int cur = it & 1;
    if (it + 1 < NIT) ISSUE_STAGE(cur ^ 1, (it + 1) * 32);  // loads in flight

    bf16x8 af[4], bfr[4];
#pragma unroll
    for (int m = 0; m < 4; ++m)
      af[m] = *(const bf16x8*)&As[cur][(wr * 64 + m * 16 + l16) * 32 + lq * 8];
#pragma unroll
    for (int n = 0; n < 4; ++n)
      bfr[n] = *(const bf16x8*)&Bs[cur][(wc * 64 + n * 16 + l16) * 32 + lq * 8];
#pragma unroll
    for (int m = 0; m < 4; ++m)
#pragma unroll
      for (int n = 0; n < 4; ++n)
        acc[m][n] =
            __builtin_amdgcn_mfma_f32_16x16x32_bf16(af[m], bfr[n], acc[m][n], 0, 0, 0);

    if (it + 1 < NIT) STORE_A(cur ^ 1);  // convert + ds_write after compute

    asm volatile("s_waitcnt vmcnt(0) lgkmcnt(0)" ::: "memory");
    __builtin_amdgcn_s_barrier();
  }
#undef ISSUE_STAGE
#undef STORE_A

  const bool vblock = V_TO_VT && (bcol >= 2 * EMBED);
#pragma unroll
  for (int m = 0; m < 4; ++m) {
    const int row = brow + wr * 64 + m * 16 + lq * 4;
#pragma unroll
    for (int n = 0; n < 4; ++n) {
      const int col = bcol + wc * 64 + n * 16 + l16;
      const float bv = bias[col];
      if (vblock) {
        bf16x4 pv;
#pragma unroll
        for (int r2 = 0; r2 < 4; ++r2) pv[r2] = (bf16)(acc[m][n][r2] + bv);
        *(bf16x4*)&vTout[(size_t)(col - 2 * EMBED) * T_SEQ + row] = pv;
      } else {
#pragma unroll
        for (int r2 = 0; r2 < 4; ++r2) {
          float v = acc[m][n][r2] + bv;
          if (OUT_F32)
            ((float*)Cout)[(size_t)(row + r2) * N + col] = v;
          else
            ((bf16*)Cout)[(size_t)(row + r2) * N + col] = (bf16)v;
        }
      }
    }
  }
}

// ---------------------------------------------------------------------------
// cvt_pk + permlane32_swap packing helper (distinct-value operands: safe).
// ---------------------------------------------------------------------------
__device__ __forceinline__ bf16x8 pk_swap8(float a0, float a1, float a2, float a3,
                                           float a4, float a5, float a6, float a7) {
  unsigned W0, W1, W2, W3;
  asm("v_cvt_pk_bf16_f32 %0, %1, %2" : "=v"(W0) : "v"(a0), "v"(a1));
  asm("v_cvt_pk_bf16_f32 %0, %1, %2" : "=v"(W1) : "v"(a2), "v"(a3));
  asm("v_cvt_pk_bf16_f32 %0, %1, %2" : "=v"(W2) : "v"(a4), "v"(a5));
  asm("v_cvt_pk_bf16_f32 %0, %1, %2" : "=v"(W3) : "v"(a6), "v"(a7));
  asm("v_permlane32_swap_b32 %0, %1" : "+v"(W0), "+v"(W2));
  asm("v_permlane32_swap_b32 %0, %1" : "+v"(W1), "+v"(W3));
  union { unsigned u[4]; bf16x8 v; } r;
  r.u[0] = W0; r.u[1] = W1; r.u[2] = W2; r.u[3] = W3;
  return r.v;
}

// ---------------------------------------------------------------------------
// Flash attention (round-16 config, the measured best): 8-wave blocks,
// QBLK=256, KVBLK=64, unshifted exp2 softmax, 2-buffer gload_lds,
// one barrier per tile, XCD head map (h = bid & 15).
// ---------------------------------------------------------------------------
__global__ __launch_bounds__(512) void flash_attn_mfma(
    const bf16* __restrict__ qkvb, const bf16* __restrict__ vT,
    bf16* __restrict__ out, bf16* __restrict__ partO_main,
    bf16* __restrict__ partO_ovf, float* __restrict__ partL) {
  const int bid = (int)blockIdx.x;
  const int h = bid & 15;
  const int job = 50 - (bid >> 4);  // big jobs (high qtb) first
  int qtb, np, part;
  if (job < 3)       { qtb = job;                       np = 1; part = 0; }
  else if (job < 9)  { int t = job - 3;  qtb = 3 + (t >> 1);  np = 2; part = t & 1; }
  else if (job < 18) { int t = job - 9;  qtb = 6 + t / 3;     np = 3; part = t - (t / 3) * 3; }
  else if (job < 30) { int t = job - 18; qtb = 9 + (t >> 2);  np = 4; part = t & 3; }
  else if (job < 45) { int t = job - 30; qtb = 12 + t / 5;    np = 5; part = t - (t / 5) * 5; }
  else               { int t = job - 45; qtb = 15;            np = 6; part = t; }
  const int nt = 4 * qtb + 4;
  const int bsz = nt / np, rem = nt % np;
  const int k0t = part * bsz + min(part, rem);
  const int k1t = k0t + bsz + (part < rem ? 1 : 0);

  int lslot = -1;
  if (np > 1) {
    if (qtb < 6)       lslot = (qtb - 3) * 2 + part;
    else if (qtb < 9)  lslot = 6 + (qtb - 6) * 3 + part;
    else if (qtb < 12) lslot = 15 + (qtb - 9) * 4 + part;
    else if (qtb < 15) lslot = 27 + (qtb - 12) * 5 + part;
    else               lslot = 42 + part;
  }

  const int q0 = qtb * 256;
  const int tid = threadIdx.x;
  const int lane = tid & 63;
  const int w = tid >> 6;        // 0..7
  const int qi = lane & 31;      // q index within wave tile
  const int hi = lane >> 5;      // k-half selector

  __shared__ __align__(16) bf16 Ks[2][64 * 64];
  __shared__ __align__(16) bf16 Vs[2][64 * 64];

  const int qrow = q0 + w * 32 + qi;

  const float QSCALE = 0.1803368867f;
  bf16x8 qb0, qb1, qb2, qb3;
  {
    const bf16* qp = &qkvb[(size_t)qrow * (3 * EMBED) + h * HDIM + hi * 8];
    qb0 = *(const bf16x8*)(qp + 0);
    qb1 = *(const bf16x8*)(qp + 16);
    qb2 = *(const bf16x8*)(qp + 32);
    qb3 = *(const bf16x8*)(qp + 48);
#pragma unroll
    for (int j = 0; j < 8; ++j) {
      qb0[j] = (bf16)((float)qb0[j] * QSCALE);
      qb1[j] = (bf16)((float)qb1[j] * QSCALE);
      qb2[j] = (bf16)((float)qb2[j] * QSCALE);
      qb3[j] = (bf16)((float)qb3[j] * QSCALE);
    }
  }

  f32x16 oA = {}, oB = {};
  float l_r = 0.f;

  const int krow = lane >> 3;
  const int ksl = ((lane & 7) ^ krow) * 8;
  const bf16* Kbase =
      qkvb + (size_t)(w * 8 + krow) * (3 * EMBED) + EMBED + h * HDIM + ksl;
  const bf16* Vbase = vT + ((size_t)h * HDIM + w * 8 + krow) * T_SEQ + ksl;

#define STAGE_KV(buf, kt)                                                  \
  {                                                                        \
    GL(Kbase + (size_t)(kt) * 64 * (3 * EMBED), &Ks[buf][(w * 8) * 64]);   \
    GL(Vbase + (kt) * 64, &Vs[buf][(w * 8) * 64]);                         \
  }

  STAGE_KV(0, k0t);
  asm volatile("s_waitcnt vmcnt(0)" ::: "memory");
  __builtin_amdgcn_s_barrier();

  for (int kt = k0t; kt < k1t; ++kt) {
    const int cur = (kt - k0t) & 1;
    if (kt + 1 < k1t) STAGE_KV(cur ^ 1, kt + 1);

    if (!(kt * 64 > q0 + w * 32 + 31)) {
      f32x16 sA = {}, sB = {};
      __builtin_amdgcn_s_setprio(1);
#pragma unroll
      for (int c = 0; c < 4; ++c) {
        const int sl = ((2 * c + hi) ^ (qi & 7)) << 3;
        bf16x8 kfA = *(const bf16x8*)&Ks[cur][qi * 64 + sl];
        bf16x8 kfB = *(const bf16x8*)&Ks[cur][(qi + 32) * 64 + sl];
        bf16x8 qf = (c == 0) ? qb0 : (c == 1) ? qb1 : (c == 2) ? qb2 : qb3;
        sA = __builtin_amdgcn_mfma_f32_32x32x16_bf16(kfA, qf, sA, 0, 0, 0);
        sB = __builtin_amdgcn_mfma_f32_32x32x16_bf16(kfB, qf, sB, 0, 0, 0);
      }
      __builtin_amdgcn_s_setprio(0);

      if (kt * 64 + 63 > q0 + w * 32) {
        const int qg = qrow;
#pragma unroll
        for (int r = 0; r < 16; ++r) {
          const int kl = (r & 3) + 8 * (r >> 2) + 4 * hi;
          if (kt * 64 + kl > qg) sA[r] = -INFINITY;
          if (kt * 64 + 32 + kl > qg) sB[r] = -INFINITY;
        }
      }

#pragma unroll
      for (int r = 0; r < 16; ++r) sA[r] = fexp2(sA[r]);
#pragma unroll
      for (int r = 0; r < 16; ++r) sB[r] = fexp2(sB[r]);

      bf16x8 pf0 = pk_swap8(sA[0], sA[1], sA[2], sA[3], sA[4], sA[5], sA[6], sA[7]);
      bf16x8 pf1 = pk_swap8(sA[8], sA[9], sA[10], sA[11], sA[12], sA[13], sA[14], sA[15]);
      bf16x8 pf2 = pk_swap8(sB[0], sB[1], sB[2], sB[3], sB[4], sB[5], sB[6], sB[7]);
      bf16x8 pf3 = pk_swap8(sB[8], sB[9], sB[10], sB[11], sB[12], sB[13], sB[14], sB[15]);

      __builtin_amdgcn_s_setprio(1);
#pragma unroll
      for (int c = 0; c < 4; ++c) {
        const int sl = ((2 * c + hi) ^ (qi & 7)) << 3;
        bf16x8 vfA = *(const bf16x8*)&Vs[cur][qi * 64 + sl];
        bf16x8 vfB = *(const bf16x8*)&Vs[cur][(qi + 32) * 64 + sl];
        bf16x8 pf = (c == 0) ? pf0 : (c == 1) ? pf1 : (c == 2) ? pf2 : pf3;
        oA = __builtin_amdgcn_mfma_f32_32x32x16_bf16(vfA, pf, oA, 0, 0, 0);
        oB = __builtin_amdgcn_mfma_f32_32x32x16_bf16(vfB, pf, oB, 0, 0, 0);
      }
      __builtin_amdgcn_s_setprio(0);

      float ts[16];
#pragma unroll
      for (int r = 0; r < 16; ++r) ts[r] = sA[r] + sB[r];
#pragma unroll
      for (int s = 8; s >= 1; s >>= 1)
#pragma unroll
        for (int r = 0; r < s; ++r) ts[r] += ts[r + s];
      l_r += ts[0];
    }

    asm volatile("s_waitcnt vmcnt(0)" ::: "memory");
    __builtin_amdgcn_s_barrier();
  }
#undef STAGE_KV

  const float lt = l_r + __shfl_xor(l_r, 32);
  const float inv = lt > 0.f ? 1.f / lt : 0.f;
#pragma unroll
  for (int r = 0; r < 16; ++r) { oA[r] *= inv; oB[r] *= inv; }

  bf16x8 e0 = pk_swap8(oA[0], oA[1], oA[2], oA[3], oA[4], oA[5], oA[6], oA[7]);
  bf16x8 e1 = pk_swap8(oA[8], oA[9], oA[10], oA[11], oA[12], oA[13], oA[14], oA[15]);
  bf16x8 e2 = pk_swap8(oB[0], oB[1], oB[2], oB[3], oB[4], oB[5], oB[6], oB[7]);
  bf16x8 e3 = pk_swap8(oB[8], oB[9], oB[10], oB[11], oB[12], oB[13], oB[14], oB[15]);

  if (lslot < 0) {
    bf16* ob = &out[(size_t)qrow * EMBED + h * HDIM];
    *(bf16x8*)(ob + hi * 8) = e0;
    *(bf16x8*)(ob + 16 + hi * 8) = e1;
    *(bf16x8*)(ob + 32 + hi * 8) = e2;
    *(bf16x8*)(ob + 48 + hi * 8) = e3;
  } else {
    const int gslot = h * 48 + lslot;  // 0..767
    bf16* base = (gslot < 512)
                     ? (bf16*)((char*)partO_main + (size_t)gslot * 32768)
                     : (bf16*)((char*)partO_ovf + (size_t)(gslot - 512) * 32768);
    const int lr = w * 32 + qi;  // 0..255
    bf16* pb = base + (size_t)lr * 64;
    *(bf16x8*)(pb + hi * 8) = e0;
    *(bf16x8*)(pb + 16 + hi * 8) = e1;
    *(bf16x8*)(pb + 32 + hi * 8) = e2;
    *(bf16x8*)(pb + 48 + hi * 8) = e3;
    if (hi == 0) partL[gslot * 256 + lr] = lt;
  }
}

// ---------------------------------------------------------------------------
// Merge 2-6 kv-split partials (256-row slots). Grid (13, HEADS), 512 thr.
// ---------------------------------------------------------------------------
__global__ __launch_bounds__(512) void merge_partials(
    const bf16* __restrict__ partO_main, const bf16* __restrict__ partO_ovf,
    const float* __restrict__ partL, bf16* __restrict__ out) {
  const int qtb = 3 + blockIdx.x;  // 3..15
  const int h = blockIdx.y;
  int np, lbase;
  if (qtb < 6)       { np = 2; lbase = (qtb - 3) * 2; }
  else if (qtb < 9)  { np = 3; lbase = 6 + (qtb - 6) * 3; }
  else if (qtb < 12) { np = 4; lbase = 15 + (qtb - 9) * 4; }
  else if (qtb < 15) { np = 5; lbase = 27 + (qtb - 12) * 5; }
  else               { np = 6; lbase = 42; }
  const int gbase = h * 48 + lbase;
  const int r = threadIdx.x >> 1;          // 0..255
  const int dh = (threadIdx.x & 1) * 32;

  float lv[6];
  float wsum = 0.f;
#pragma unroll
  for (int p = 0; p < 6; ++p)
    if (p < np) {
      lv[p] = partL[(gbase + p) * 256 + r];
      wsum += lv[p];
    }
  const float inv = wsum > 0.f ? 1.f / wsum : 0.f;
  float wgt[6];
#pragma unroll
  for (int p = 0; p < 6; ++p)
    if (p < np) wgt[p] = lv[p] * inv;

  const bf16* pp[6];
#pragma unroll
  for (int p = 0; p < 6; ++p)
    if (p < np) {
      const int gs = gbase + p;
      const bf16* base = (gs < 512)
                             ? (const bf16*)((const char*)partO_main + (size_t)gs * 32768)
                             : (const bf16*)((const char*)partO_ovf + (size_t)(gs - 512) * 32768);
      pp[p] = base + (size_t)r * 64 + dh;
    }

  bf16* ob = &out[(size_t)(qtb * 256 + r) * EMBED + h * HDIM + dh];
#pragma unroll
  for (int c = 0; c < 4; ++c) {
    float acc[8] = {0.f, 0.f, 0.f, 0.f, 0.f, 0.f, 0.f, 0.f};
#pragma unroll
    for (int p = 0; p < 6; ++p)
      if (p < np) {
        bf16x8 v = *(const bf16x8*)(pp[p] + c * 8);
#pragma unroll
        for (int j = 0; j < 8; ++j) acc[j] += wgt[p] * (float)v[j];
      }
    bf16x8 o;
#pragma unroll
    for (int j = 0; j < 8; ++j) o[j] = (bf16)acc[j];
    *(bf16x8*)(ob + c * 8) = o;
  }
}

// ---------------------------------------------------------------------------
extern "C" void kernel_launch(void* const* d_in, const int* in_sizes, int n_in,
                              void* d_out, int out_size, void* d_ws, size_t ws_size,
                              hipStream_t stream) {
  const float* x     = (const float*)d_in[0];
  const float* W_qkv = (const float*)d_in[1];
  const float* b_qkv = (const float*)d_in[2];
  const float* W_out = (const float*)d_in[3];
  const float* b_out = (const float*)d_in[4];
  float* out = (float*)d_out;

  char* ws = (char*)d_ws;
  const size_t MB = 1024 * 1024;
  // x_bf eliminated: ws+0 now only hosts kv-split overflow partials.
  bf16* WqkvT  = (bf16*)(ws + 8 * MB);   // 6 MB
  bf16* WoutT  = (bf16*)(ws + 14 * MB);  // 2 MB (live to end)
  bf16* qkvb   = (bf16*)(ws + 16 * MB);  // 24 MB (V third unused)
  bf16* vT     = (bf16*)(ws + 40 * MB);  // 8 MB (written by QKV gemm epilogue)
  bf16* attn_o = (bf16*)(ws + 48 * MB);  // 8 MB
  // kv-split partials: 768 slots x 32 KB. 0..511 in d_out (rewritten by
  // final GEMM), 512..767 over ws+0. partL after WqkvT region? No: partL
  // overlays WqkvT only AFTER it is dead -- keep partL in its own spot:
  // WqkvT stays live through the QKV GEMM; flash writes partL after.
  bf16*  partO_main = (bf16*)d_out;
  bf16*  partO_ovf  = (bf16*)(ws + 0);
  float* partL      = (float*)(ws + 8 * MB);  // over WqkvT (dead post-QKV GEMM)

  // weight transposes only (x conversion fused into the QKV GEMM).
  prep<<<dim3(4096), 256, 0, stream>>>(W_qkv, W_out, WqkvT, WoutT);

  // QKV projection, A read directly from fp32 x; V third -> vT.
  gemm_bt_bias<false, true, true><<<dim3((T_SEQ / 128) * (3 * EMBED / 128)), 256, 0,
                                    stream>>>(x, WqkvT, b_qkv, qkvb, vT, T_SEQ,
                                              3 * EMBED, EMBED);

  flash_attn_mfma<<<dim3(51 * HEADS), 512, 0, stream>>>(qkvb, vT, attn_o, partO_main,
                                                        partO_ovf, partL);
  merge_partials<<<dim3(13, HEADS), 512, 0, stream>>>(partO_main, partO_ovf, partL,
                                                      attn_o);

  // Output projection (bf16 A, unchanged path).
  gemm_bt_bias<true, false, false><<<dim3((T_SEQ / 128) * (EMBED / 128)), 256, 0,
                                     stream>>>(attn_o, WoutT, b_out, out, nullptr,
                                               T_SEQ, EMBED, EMBED);
}

// Round 22
// 130.304 us; speedup vs baseline: 1.0189x; 1.0189x over previous
//
#include <hip/hip_runtime.h>
#include <hip/hip_bf16.h>
#include <math.h>

#define EMBED 1024
#define HEADS 16
#define HDIM 64
#define T_SEQ 4096

typedef __bf16 bf16;
typedef bf16 bf16x4 __attribute__((ext_vector_type(4)));
typedef bf16 bf16x8 __attribute__((ext_vector_type(8)));
typedef float f32x4 __attribute__((ext_vector_type(4)));
typedef float f32x16 __attribute__((ext_vector_type(16)));

// async global->LDS, 16B per lane; LDS dest = wave-uniform base + lane*16.
#define GL(gp, lp)                                                            \
  __builtin_amdgcn_global_load_lds(                                           \
      (const __attribute__((address_space(1))) void*)(gp),                    \
      (__attribute__((address_space(3))) void*)(lp), 16, 0, 0)

// hardware 2^x
__device__ __forceinline__ float fexp2(float x) {
  float r;
  asm("v_exp_f32 %0, %1" : "=v"(r) : "v"(x));
  return r;
}

// ---------------------------------------------------------------------------
// Fused prep: blocks 0..2047 convert x (fp32->bf16, 8 elems/thread);
// blocks 2048..6143 transpose both weight matrices to bf16 [cols][rows].
// ---------------------------------------------------------------------------
__global__ __launch_bounds__(256) void prep(
    const float* __restrict__ x, const float* __restrict__ Wqkv,
    const float* __restrict__ Wout, bf16* __restrict__ x_bf,
    bf16* __restrict__ WqkvT, bf16* __restrict__ WoutT) {
  int b = (int)blockIdx.x;
  if (b < 2048) {
    const int i = (b * 256 + (int)threadIdx.x) * 8;
    float4 a = *(const float4*)&x[i];
    float4 c = *(const float4*)&x[i + 4];
    bf16x8 o;
    o[0] = (bf16)a.x; o[1] = (bf16)a.y; o[2] = (bf16)a.z; o[3] = (bf16)a.w;
    o[4] = (bf16)c.x; o[5] = (bf16)c.y; o[6] = (bf16)c.z; o[7] = (bf16)c.w;
    *(bf16x8*)&x_bf[i] = o;
    return;
  }
  b -= 2048;
  __shared__ bf16 t[32][33];
  const int bx = b & 127, by = b >> 7;
  const int rows = 1024;
  const float* in;
  bf16* out;
  int c0, cols;
  if (bx < 96) { in = Wqkv; out = WqkvT; c0 = bx * 32; cols = 3072; }
  else         { in = Wout; out = WoutT; c0 = (bx - 96) * 32; cols = 1024; }
  const int r0 = by * 32;
  const int tx = threadIdx.x & 31, ty = threadIdx.x >> 5;
#pragma unroll
  for (int i = 0; i < 4; ++i)
    t[ty + 8 * i][tx] = (bf16)in[(size_t)(r0 + ty + 8 * i) * cols + c0 + tx];
  __syncthreads();
#pragma unroll
  for (int i = 0; i < 4; ++i)
    out[(size_t)(c0 + ty + 8 * i) * rows + r0 + tx] = t[tx][ty + 8 * i];
}

// ---------------------------------------------------------------------------
// bf16 MFMA GEMM (round-16 config): 128x128 tile, 4 waves, BK=32,
// gload_lds dbuf, single barrier per K-step, XCD-aware 1-D grid
// (xcd = bid & 7 owns 4 row-blocks, row-fastest).
// ---------------------------------------------------------------------------
template <bool OUT_F32, bool V_TO_VT>
__global__ __launch_bounds__(256) void gemm_bt_bias(
    const bf16* __restrict__ A, const bf16* __restrict__ BT,
    const float* __restrict__ bias, void* __restrict__ Cout,
    bf16* __restrict__ vTout, int M, int N, int K) {
  __shared__ __align__(16) bf16 As[2][128 * 32];
  __shared__ __align__(16) bf16 Bs[2][128 * 32];
  const int tid = threadIdx.x;
  const int lane = tid & 63;
  const int w = tid >> 6;
  const int wr = w >> 1, wc = w & 1;
  const int l16 = lane & 15, lq = lane >> 4;

  const int bid = (int)blockIdx.x;
  const int xcd = bid & 7;
  const int local = bid >> 3;
  const int brow = (xcd * 4 + (local & 3)) * 128;
  const int bcol = (local >> 2) * 128;

  const int strow = w * 32 + (lane >> 2);
  const int stsl = (lane & 3) * 8;
  const bf16* Abase = A + (size_t)(brow + strow) * K + stsl;
  const bf16* Bbase = BT + (size_t)(bcol + strow) * K + stsl;

#define STAGE_G(buf, k0)                                        \
  {                                                             \
    GL(Abase + (k0), &As[buf][(w * 32) * 32]);                  \
    GL(Abase + (k0) + 16 * K, &As[buf][(w * 32 + 16) * 32]);    \
    GL(Bbase + (k0), &Bs[buf][(w * 32) * 32]);                  \
    GL(Bbase + (k0) + 16 * K, &Bs[buf][(w * 32 + 16) * 32]);    \
  }

  f32x4 acc[4][4] = {};
  const int NIT = K / 32;

  STAGE_G(0, 0);
  asm volatile("s_waitcnt vmcnt(0)" ::: "memory");
  __builtin_amdgcn_s_barrier();

  for (int it = 0; it < NIT; ++it) {
    const int cur = it & 1;
    if (it + 1 < NIT) STAGE_G(cur ^ 1, (it + 1) * 32);

    bf16x8 af[4], bfr[4];
#pragma unroll
    for (int m = 0; m < 4; ++m)
      af[m] = *(const bf16x8*)&As[cur][(wr * 64 + m * 16 + l16) * 32 + lq * 8];
#pragma unroll
    for (int n = 0; n < 4; ++n)
      bfr[n] = *(const bf16x8*)&Bs[cur][(wc * 64 + n * 16 + l16) * 32 + lq * 8];
#pragma unroll
    for (int m = 0; m < 4; ++m)
#pragma unroll
      for (int n = 0; n < 4; ++n)
        acc[m][n] =
            __builtin_amdgcn_mfma_f32_16x16x32_bf16(af[m], bfr[n], acc[m][n], 0, 0, 0);

    asm volatile("s_waitcnt vmcnt(0)" ::: "memory");
    __builtin_amdgcn_s_barrier();
  }
#undef STAGE_G

  const bool vblock = V_TO_VT && (bcol >= 2 * EMBED);
#pragma unroll
  for (int m = 0; m < 4; ++m) {
    const int row = brow + wr * 64 + m * 16 + lq * 4;
#pragma unroll
    for (int n = 0; n < 4; ++n) {
      const int col = bcol + wc * 64 + n * 16 + l16;
      const float bv = bias[col];
      if (vblock) {
        bf16x4 pv;
#pragma unroll
        for (int r2 = 0; r2 < 4; ++r2) pv[r2] = (bf16)(acc[m][n][r2] + bv);
        *(bf16x4*)&vTout[(size_t)(col - 2 * EMBED) * T_SEQ + row] = pv;
      } else {
#pragma unroll
        for (int r2 = 0; r2 < 4; ++r2) {
          float v = acc[m][n][r2] + bv;
          if (OUT_F32)
            ((float*)Cout)[(size_t)(row + r2) * N + col] = v;
          else
            ((bf16*)Cout)[(size_t)(row + r2) * N + col] = (bf16)v;
        }
      }
    }
  }
}

// ---------------------------------------------------------------------------
// cvt_pk + permlane32_swap packing helper (distinct-value operands: safe).
// ---------------------------------------------------------------------------
__device__ __forceinline__ bf16x8 pk_swap8(float a0, float a1, float a2, float a3,
                                           float a4, float a5, float a6, float a7) {
  unsigned W0, W1, W2, W3;
  asm("v_cvt_pk_bf16_f32 %0, %1, %2" : "=v"(W0) : "v"(a0), "v"(a1));
  asm("v_cvt_pk_bf16_f32 %0, %1, %2" : "=v"(W1) : "v"(a2), "v"(a3));
  asm("v_cvt_pk_bf16_f32 %0, %1, %2" : "=v"(W2) : "v"(a4), "v"(a5));
  asm("v_cvt_pk_bf16_f32 %0, %1, %2" : "=v"(W3) : "v"(a6), "v"(a7));
  asm("v_permlane32_swap_b32 %0, %1" : "+v"(W0), "+v"(W2));
  asm("v_permlane32_swap_b32 %0, %1" : "+v"(W1), "+v"(W3));
  union { unsigned u[4]; bf16x8 v; } r;
  r.u[0] = W0; r.u[1] = W1; r.u[2] = W2; r.u[3] = W3;
  return r.v;
}

// ---------------------------------------------------------------------------
// Flash attention (round-16 config, the measured best): 8-wave blocks,
// QBLK=256, KVBLK=64, unshifted exp2 softmax, 2-buffer gload_lds (1 GL K +
// 1 GL V per wave per tile), one barrier per tile, XCD head map
// (h = bid & 15 -> 2 heads per XCD L2).
// ---------------------------------------------------------------------------
__global__ __launch_bounds__(512) void flash_attn_mfma(
    const bf16* __restrict__ qkvb, const bf16* __restrict__ vT,
    bf16* __restrict__ out, bf16* __restrict__ partO_main,
    bf16* __restrict__ partO_ovf, float* __restrict__ partL) {
  const int bid = (int)blockIdx.x;
  const int h = bid & 15;
  const int job = 50 - (bid >> 4);  // big jobs (high qtb) first
  int qtb, np, part;
  if (job < 3)       { qtb = job;                       np = 1; part = 0; }
  else if (job < 9)  { int t = job - 3;  qtb = 3 + (t >> 1);  np = 2; part = t & 1; }
  else if (job < 18) { int t = job - 9;  qtb = 6 + t / 3;     np = 3; part = t - (t / 3) * 3; }
  else if (job < 30) { int t = job - 18; qtb = 9 + (t >> 2);  np = 4; part = t & 3; }
  else if (job < 45) { int t = job - 30; qtb = 12 + t / 5;    np = 5; part = t - (t / 5) * 5; }
  else               { int t = job - 45; qtb = 15;            np = 6; part = t; }
  const int nt = 4 * qtb + 4;
  const int bsz = nt / np, rem = nt % np;
  const int k0t = part * bsz + min(part, rem);
  const int k1t = k0t + bsz + (part < rem ? 1 : 0);

  int lslot = -1;
  if (np > 1) {
    if (qtb < 6)       lslot = (qtb - 3) * 2 + part;
    else if (qtb < 9)  lslot = 6 + (qtb - 6) * 3 + part;
    else if (qtb < 12) lslot = 15 + (qtb - 9) * 4 + part;
    else if (qtb < 15) lslot = 27 + (qtb - 12) * 5 + part;
    else               lslot = 42 + part;
  }

  const int q0 = qtb * 256;
  const int tid = threadIdx.x;
  const int lane = tid & 63;
  const int w = tid >> 6;        // 0..7
  const int qi = lane & 31;      // q index within wave tile
  const int hi = lane >> 5;      // k-half selector

  __shared__ __align__(16) bf16 Ks[2][64 * 64];
  __shared__ __align__(16) bf16 Vs[2][64 * 64];

  const int qrow = q0 + w * 32 + qi;

  const float QSCALE = 0.1803368867f;
  bf16x8 qb0, qb1, qb2, qb3;
  {
    const bf16* qp = &qkvb[(size_t)qrow * (3 * EMBED) + h * HDIM + hi * 8];
    qb0 = *(const bf16x8*)(qp + 0);
    qb1 = *(const bf16x8*)(qp + 16);
    qb2 = *(const bf16x8*)(qp + 32);
    qb3 = *(const bf16x8*)(qp + 48);
#pragma unroll
    for (int j = 0; j < 8; ++j) {
      qb0[j] = (bf16)((float)qb0[j] * QSCALE);
      qb1[j] = (bf16)((float)qb1[j] * QSCALE);
      qb2[j] = (bf16)((float)qb2[j] * QSCALE);
      qb3[j] = (bf16)((float)qb3[j] * QSCALE);
    }
  }

  f32x16 oA = {}, oB = {};
  float l_r = 0.f;

  const int krow = lane >> 3;
  const int ksl = ((lane & 7) ^ krow) * 8;
  const bf16* Kbase =
      qkvb + (size_t)(w * 8 + krow) * (3 * EMBED) + EMBED + h * HDIM + ksl;
  const bf16* Vbase = vT + ((size_t)h * HDIM + w * 8 + krow) * T_SEQ + ksl;

#define STAGE_KV(buf, kt)                                                  \
  {                                                                        \
    GL(Kbase + (size_t)(kt) * 64 * (3 * EMBED), &Ks[buf][(w * 8) * 64]);   \
    GL(Vbase + (kt) * 64, &Vs[buf][(w * 8) * 64]);                         \
  }

  STAGE_KV(0, k0t);
  asm volatile("s_waitcnt vmcnt(0)" ::: "memory");
  __builtin_amdgcn_s_barrier();

  for (int kt = k0t; kt < k1t; ++kt) {
    const int cur = (kt - k0t) & 1;
    if (kt + 1 < k1t) STAGE_KV(cur ^ 1, kt + 1);

    if (!(kt * 64 > q0 + w * 32 + 31)) {
      f32x16 sA = {}, sB = {};
      __builtin_amdgcn_s_setprio(1);
#pragma unroll
      for (int c = 0; c < 4; ++c) {
        const int sl = ((2 * c + hi) ^ (qi & 7)) << 3;
        bf16x8 kfA = *(const bf16x8*)&Ks[cur][qi * 64 + sl];
        bf16x8 kfB = *(const bf16x8*)&Ks[cur][(qi + 32) * 64 + sl];
        bf16x8 qf = (c == 0) ? qb0 : (c == 1) ? qb1 : (c == 2) ? qb2 : qb3;
        sA = __builtin_amdgcn_mfma_f32_32x32x16_bf16(kfA, qf, sA, 0, 0, 0);
        sB = __builtin_amdgcn_mfma_f32_32x32x16_bf16(kfB, qf, sB, 0, 0, 0);
      }
      __builtin_amdgcn_s_setprio(0);

      if (kt * 64 + 63 > q0 + w * 32) {
        const int qg = qrow;
#pragma unroll
        for (int r = 0; r < 16; ++r) {
          const int kl = (r & 3) + 8 * (r >> 2) + 4 * hi;
          if (kt * 64 + kl > qg) sA[r] = -INFINITY;
          if (kt * 64 + 32 + kl > qg) sB[r] = -INFINITY;
        }
      }

#pragma unroll
      for (int r = 0; r < 16; ++r) sA[r] = fexp2(sA[r]);
#pragma unroll
      for (int r = 0; r < 16; ++r) sB[r] = fexp2(sB[r]);

      bf16x8 pf0 = pk_swap8(sA[0], sA[1], sA[2], sA[3], sA[4], sA[5], sA[6], sA[7]);
      bf16x8 pf1 = pk_swap8(sA[8], sA[9], sA[10], sA[11], sA[12], sA[13], sA[14], sA[15]);
      bf16x8 pf2 = pk_swap8(sB[0], sB[1], sB[2], sB[3], sB[4], sB[5], sB[6], sB[7]);
      bf16x8 pf3 = pk_swap8(sB[8], sB[9], sB[10], sB[11], sB[12], sB[13], sB[14], sB[15]);

      __builtin_amdgcn_s_setprio(1);
#pragma unroll
      for (int c = 0; c < 4; ++c) {
        const int sl = ((2 * c + hi) ^ (qi & 7)) << 3;
        bf16x8 vfA = *(const bf16x8*)&Vs[cur][qi * 64 + sl];
        bf16x8 vfB = *(const bf16x8*)&Vs[cur][(qi + 32) * 64 + sl];
        bf16x8 pf = (c == 0) ? pf0 : (c == 1) ? pf1 : (c == 2) ? pf2 : pf3;
        oA = __builtin_amdgcn_mfma_f32_32x32x16_bf16(vfA, pf, oA, 0, 0, 0);
        oB = __builtin_amdgcn_mfma_f32_32x32x16_bf16(vfB, pf, oB, 0, 0, 0);
      }
      __builtin_amdgcn_s_setprio(0);

      float ts[16];
#pragma unroll
      for (int r = 0; r < 16; ++r) ts[r] = sA[r] + sB[r];
#pragma unroll
      for (int s = 8; s >= 1; s >>= 1)
#pragma unroll
        for (int r = 0; r < s; ++r) ts[r] += ts[r + s];
      l_r += ts[0];
    }

    asm volatile("s_waitcnt vmcnt(0)" ::: "memory");
    __builtin_amdgcn_s_barrier();
  }
#undef STAGE_KV

  const float lt = l_r + __shfl_xor(l_r, 32);
  const float inv = lt > 0.f ? 1.f / lt : 0.f;
#pragma unroll
  for (int r = 0; r < 16; ++r) { oA[r] *= inv; oB[r] *= inv; }

  bf16x8 e0 = pk_swap8(oA[0], oA[1], oA[2], oA[3], oA[4], oA[5], oA[6], oA[7]);
  bf16x8 e1 = pk_swap8(oA[8], oA[9], oA[10], oA[11], oA[12], oA[13], oA[14], oA[15]);
  bf16x8 e2 = pk_swap8(oB[0], oB[1], oB[2], oB[3], oB[4], oB[5], oB[6], oB[7]);
  bf16x8 e3 = pk_swap8(oB[8], oB[9], oB[10], oB[11], oB[12], oB[13], oB[14], oB[15]);

  if (lslot < 0) {
    bf16* ob = &out[(size_t)qrow * EMBED + h * HDIM];
    *(bf16x8*)(ob + hi * 8) = e0;
    *(bf16x8*)(ob + 16 + hi * 8) = e1;
    *(bf16x8*)(ob + 32 + hi * 8) = e2;
    *(bf16x8*)(ob + 48 + hi * 8) = e3;
  } else {
    const int gslot = h * 48 + lslot;  // 0..767
    bf16* base = (gslot < 512)
                     ? (bf16*)((char*)partO_main + (size_t)gslot * 32768)
                     : (bf16*)((char*)partO_ovf + (size_t)(gslot - 512) * 32768);
    const int lr = w * 32 + qi;  // 0..255
    bf16* pb = base + (size_t)lr * 64;
    *(bf16x8*)(pb + hi * 8) = e0;
    *(bf16x8*)(pb + 16 + hi * 8) = e1;
    *(bf16x8*)(pb + 32 + hi * 8) = e2;
    *(bf16x8*)(pb + 48 + hi * 8) = e3;
    if (hi == 0) partL[gslot * 256 + lr] = lt;
  }
}

// ---------------------------------------------------------------------------
// Merge 2-6 kv-split partials (256-row slots). Grid (13, HEADS), 512 thr.
// Unshifted softmax -> weights l_p / sum(l_p).
// ---------------------------------------------------------------------------
__global__ __launch_bounds__(512) void merge_partials(
    const bf16* __restrict__ partO_main, const bf16* __restrict__ partO_ovf,
    const float* __restrict__ partL, bf16* __restrict__ out) {
  const int qtb = 3 + blockIdx.x;  // 3..15
  const int h = blockIdx.y;
  int np, lbase;
  if (qtb < 6)       { np = 2; lbase = (qtb - 3) * 2; }
  else if (qtb < 9)  { np = 3; lbase = 6 + (qtb - 6) * 3; }
  else if (qtb < 12) { np = 4; lbase = 15 + (qtb - 9) * 4; }
  else if (qtb < 15) { np = 5; lbase = 27 + (qtb - 12) * 5; }
  else               { np = 6; lbase = 42; }
  const int gbase = h * 48 + lbase;
  const int r = threadIdx.x >> 1;          // 0..255
  const int dh = (threadIdx.x & 1) * 32;

  float lv[6];
  float wsum = 0.f;
#pragma unroll
  for (int p = 0; p < 6; ++p)
    if (p < np) {
      lv[p] = partL[(gbase + p) * 256 + r];
      wsum += lv[p];
    }
  const float inv = wsum > 0.f ? 1.f / wsum : 0.f;
  float wgt[6];
#pragma unroll
  for (int p = 0; p < 6; ++p)
    if (p < np) wgt[p] = lv[p] * inv;

  const bf16* pp[6];
#pragma unroll
  for (int p = 0; p < 6; ++p)
    if (p < np) {
      const int gs = gbase + p;
      const bf16* base = (gs < 512)
                             ? (const bf16*)((const char*)partO_main + (size_t)gs * 32768)
                             : (const bf16*)((const char*)partO_ovf + (size_t)(gs - 512) * 32768);
      pp[p] = base + (size_t)r * 64 + dh;
    }

  bf16* ob = &out[(size_t)(qtb * 256 + r) * EMBED + h * HDIM + dh];
#pragma unroll
  for (int c = 0; c < 4; ++c) {
    float acc[8] = {0.f, 0.f, 0.f, 0.f, 0.f, 0.f, 0.f, 0.f};
#pragma unroll
    for (int p = 0; p < 6; ++p)
      if (p < np) {
        bf16x8 v = *(const bf16x8*)(pp[p] + c * 8);
#pragma unroll
        for (int j = 0; j < 8; ++j) acc[j] += wgt[p] * (float)v[j];
      }
    bf16x8 o;
#pragma unroll
    for (int j = 0; j < 8; ++j) o[j] = (bf16)acc[j];
    *(bf16x8*)(ob + c * 8) = o;
  }
}

// ---------------------------------------------------------------------------
extern "C" void kernel_launch(void* const* d_in, const int* in_sizes, int n_in,
                              void* d_out, int out_size, void* d_ws, size_t ws_size,
                              hipStream_t stream) {
  const float* x     = (const float*)d_in[0];
  const float* W_qkv = (const float*)d_in[1];
  const float* b_qkv = (const float*)d_in[2];
  const float* W_out = (const float*)d_in[3];
  const float* b_out = (const float*)d_in[4];
  float* out = (float*)d_out;

  char* ws = (char*)d_ws;
  const size_t MB = 1024 * 1024;
  bf16* x_bf   = (bf16*)(ws + 0);        // 8 MB; dead after QKV gemm
  bf16* WqkvT  = (bf16*)(ws + 8 * MB);   // 6 MB; dead after QKV gemm
  bf16* WoutT  = (bf16*)(ws + 14 * MB);  // 2 MB (live to end)
  bf16* qkvb   = (bf16*)(ws + 16 * MB);  // 24 MB (V third unused)
  bf16* vT     = (bf16*)(ws + 40 * MB);  // 8 MB (written by QKV gemm epilogue)
  bf16* attn_o = (bf16*)(ws + 48 * MB);  // 8 MB
  // kv-split partials: 768 slots x 32 KB. 0..511 in d_out (rewritten by
  // final GEMM), 512..767 over dead x_bf. partL over WqkvT.
  bf16*  partO_main = (bf16*)d_out;
  bf16*  partO_ovf  = (bf16*)(ws + 0);
  float* partL      = (float*)(ws + 8 * MB);

  // fused prep: x conversion (2048 blocks) + both weight transposes (4096).
  prep<<<dim3(6144), 256, 0, stream>>>(x, W_qkv, W_out, x_bf, WqkvT, WoutT);

  // QKV projection (XCD-swizzled 1-D grid, 768 blocks); V third -> vT.
  gemm_bt_bias<false, true><<<dim3((T_SEQ / 128) * (3 * EMBED / 128)), 256, 0,
                              stream>>>(x_bf, WqkvT, b_qkv, qkvb, vT, T_SEQ,
                                        3 * EMBED, EMBED);

  flash_attn_mfma<<<dim3(51 * HEADS), 512, 0, stream>>>(qkvb, vT, attn_o, partO_main,
                                                        partO_ovf, partL);
  merge_partials<<<dim3(13, HEADS), 512, 0, stream>>>(partO_main, partO_ovf, partL,
                                                      attn_o);

  // Output projection (XCD-swizzled 1-D grid, 256 blocks).
  gemm_bt_bias<true, false><<<dim3((T_SEQ / 128) * (EMBED / 128)), 256, 0, stream>>>(
      attn_o, WoutT, b_out, out, nullptr, T_SEQ, EMBED, EMBED);
}